// Round 10
// baseline (524.145 us; speedup 1.0000x reference)
//
#include <hip/hip_runtime.h>
#include <hip/hip_bf16.h>

// Problem constants (B=1)
#define S_LEN 4096
#define HID 2048
#define NH 16
#define NKV 4
#define HD 128        // D
#define MSK 32        // M (sketch dim)
#define KTOP 8
#define NBLK 64       // S/BLK
#define NEGV -1000000000.0f
#define SENT -3.0e38f

typedef __hip_bfloat16 bf16;
typedef __attribute__((ext_vector_type(8))) short short8;   // 8 bf16 (4 VGPR)
typedef __attribute__((ext_vector_type(4))) float f32x4;

// EMPIRICAL (R1-R19): Selection needs bf16x3 (hi*hi+hi*lo+lo*hi, fp32 accum);
// V plain bf16. Proj MUST keep >=3 blocks/CU residency (R13 lesson).
// R15 (PROVEN): swizzled 8KB tile images + global_load_lds staging.
// R16 LESSON: XCD swizzle grouping units per XCD HURT. R17 LESSON: attn T14
// reg prefetch REGRESSED (spill under VGPR cap). R18: merged prepass (455us).
// R19: attn drops KV LDS staging entirely -- K/V are L2-resident (2MB per
// head-group), B-fragments loaded per-lane direct from global (kf/vfT are
// 16B-aligned at fragment addresses); main loop becomes BARRIER-FREE, LDS
// 45KB->9KB (guide common-mistake #7: don't LDS-stage L2-fit data).

__device__ __forceinline__ unsigned short f2b(float v) {
    __hip_bfloat16 h = __float2bfloat16(v);
    return *reinterpret_cast<unsigned short*>(&h);
}
__device__ __forceinline__ float b2f(unsigned short u) {
    return __bfloat162float(*reinterpret_cast<__hip_bfloat16*>(&u));
}
__device__ __forceinline__ void gl16(const void* g, void* l) {
    __builtin_amdgcn_global_load_lds(
        (const __attribute__((address_space(1))) void*)g,
        (__attribute__((address_space(3))) void*)l, 16, 0, 0);
}

// ---------------------------------------------------------------------------
// MERGED pre-pass (one launch):
//  blocks [0, nA)          : hidden A -> tiled/swizzled hi+lo 8KB images
//  blocks [nA, nA+1536)    : W Q/K/V -> per-head 64 swizzled 8KB k-tiles
//  blocks [nA+1536, +nWo)  : Wo -> bf16 hi, transposed linear [n][k]
// Tile image format: [128 rows][32 k] bf16, chunk(row,lq)=((row*4+lq)^(row&7)),
// each chunk = 16B of 8 consecutive k shorts.
// ---------------------------------------------------------------------------
__global__ __launch_bounds__(256) void prepass(
    const float* __restrict__ Wq, const float* __restrict__ Wk,
    const float* __restrict__ Wv, const float* __restrict__ Wo,
    const float* __restrict__ A,
    bf16* __restrict__ WtqH, bf16* __restrict__ WtqL,
    bf16* __restrict__ WtkH, bf16* __restrict__ WtkL,
    bf16* __restrict__ WtvH, bf16* __restrict__ WtoH,
    bf16* __restrict__ AhiT, bf16* __restrict__ AloT,
    int nA) {
    __shared__ __align__(16) float LsArena[64 * 68];   // 17408B, both W shapes fit
    const int t = threadIdx.x;
    int bx = blockIdx.x;

    if (bx < nA) {        // ---- A tiles ----
        const int rb = bx >> 6, kt = bx & 63;
        char* DH = (char*)AhiT + ((size_t)rb * 64 + kt) * 8192;
        char* DL = (char*)AloT + ((size_t)rb * 64 + kt) * 8192;
#pragma unroll
        for (int i = 0; i < 2; i++) {
            const int task = t + i * 256;
            const int row = task >> 2, lq = task & 3;
            const float* ap = &A[(size_t)(rb * 128 + row) * HID + kt * 32 + lq * 8];
            const float4 v0 = *(const float4*)ap;
            const float4 v1 = *(const float4*)(ap + 4);
            const float f[8] = {v0.x, v0.y, v0.z, v0.w, v1.x, v1.y, v1.z, v1.w};
            alignas(16) unsigned short hh[8], lo[8];
#pragma unroll
            for (int j = 0; j < 8; j++) {
                hh[j] = f2b(f[j]);
                lo[j] = f2b(f[j] - b2f(hh[j]));
            }
            const size_t off = (size_t)(((row * 4 + lq) ^ (row & 7))) * 16;
            *(uint4*)(DH + off) = *(const uint4*)hh;
            *(uint4*)(DL + off) = *(const uint4*)lo;
        }
        return;
    }
    bx -= nA;

    if (bx < 1536) {      // ---- W Q/K/V tiles ----
        const int u = bx >> 6, kt = bx & 63, k0 = kt * 32;
        const float* W; char* TH; char* TL; int Nd, n0; bool hasLo;
        if (u < 16)      { W = Wq; TH = (char*)WtqH + (size_t)u * 524288;        TL = (char*)WtqL + (size_t)u * 524288; Nd = 2048; n0 = u * 128; hasLo = true; }
        else if (u < 20) { W = Wk; TH = (char*)WtkH + (size_t)(u - 16) * 524288; TL = (char*)WtkL + (size_t)(u - 16) * 524288; Nd = 512; n0 = (u - 16) * 128; hasLo = true; }
        else             { W = Wv; TH = (char*)WtvH + (size_t)(u - 20) * 524288; TL = nullptr; Nd = 512; n0 = (u - 20) * 128; hasLo = false; }
        float(*Lw)[132] = (float(*)[132])LsArena;
#pragma unroll
        for (int i = 0; i < 4; i++) {            // 32k x 128n fp32, coalesced
            const int task = t + i * 256;
            const int k = task >> 5, c4 = task & 31;
            *(float4*)&Lw[k][c4 * 4] = *(const float4*)&W[(size_t)(k0 + k) * Nd + n0 + c4 * 4];
        }
        __syncthreads();
#pragma unroll
        for (int i = 0; i < 2; i++) {            // 512 chunks
            const int task = t + i * 256;
            const int col = task >> 2, lq = task & 3;
            alignas(16) unsigned short hh[8], lo[8];
#pragma unroll
            for (int j = 0; j < 8; j++) {
                const float x = Lw[lq * 8 + j][col];
                hh[j] = f2b(x);
                lo[j] = f2b(x - b2f(hh[j]));
            }
            const size_t off = (size_t)kt * 8192 + (size_t)(((col * 4 + lq) ^ (col & 7))) * 16;
            *(uint4*)(TH + off) = *(const uint4*)hh;
            if (hasLo) *(uint4*)(TL + off) = *(const uint4*)lo;
        }
        return;
    }
    bx -= 1536;

    {                     // ---- Wo transpose ----
        const int n0 = (bx >> 5) * 64, k0 = (bx & 31) * 64;
        float(*Ls)[68] = (float(*)[68])LsArena;
        {
            const int kk = t >> 2, c0 = (t & 3) * 16;
#pragma unroll
            for (int i = 0; i < 4; i++)
                *(float4*)&Ls[kk][c0 + i * 4] =
                    *(const float4*)&Wo[(size_t)(k0 + kk) * HID + n0 + c0 + i * 4];
        }
        __syncthreads();
        const int c = t >> 2, ks = (t & 3) * 16;
        alignas(16) unsigned short hh[16];
#pragma unroll
        for (int j = 0; j < 16; j++) hh[j] = f2b(Ls[ks + j][c]);
        unsigned short* TH = (unsigned short*)WtoH;
        const size_t db = (size_t)(n0 + c) * HID + k0 + ks;
        *(uint4*)&TH[db + 0] = *(const uint4*)&hh[0];
        *(uint4*)&TH[db + 8] = *(const uint4*)&hh[8];
    }
}

// ---------------------------------------------------------------------------
// proj4: Q/K/V projection + RoPE + sketch. 2D grid (24 units, 32 row-blocks),
// DEFAULT dispatch order (R16 lesson). Staging via global_load_lds from
// swizzled tile images; frag ds_read applies the XOR.
// ---------------------------------------------------------------------------
__global__ __launch_bounds__(256, 3) void proj4(
    const float* __restrict__ A,
    const bf16* __restrict__ AhiT_, const bf16* __restrict__ AloT_,
    const bf16* __restrict__ WtqH_, const bf16* __restrict__ WtqL_,
    const bf16* __restrict__ WtkH_, const bf16* __restrict__ WtkL_,
    const bf16* __restrict__ WtvH_,
    const int* __restrict__ pos_ids, const float* __restrict__ H,
    bf16* __restrict__ qf, bf16* __restrict__ kf, bf16* __restrict__ vfT,
    float* __restrict__ Sq, float* __restrict__ Sk) {
    const int u = blockIdx.x;
    const int rb = blockIdx.y;
    const bool isQ = (u < 16);
    const bool isV = (u >= 20);
    const bool np3 = !isV;
    const int h = isQ ? u : (isV ? (u - 20) : (u - 16));
    const char* WHb = (const char*)(isQ ? WtqH_ : (isV ? WtvH_ : WtkH_)) + (size_t)h * 524288;
    const char* WLb = (const char*)(isQ ? WtqL_ : WtkL_) + (size_t)h * 524288; // not deref'd for V
    const char* AHb = (const char*)AhiT_;
    const char* ALb = (const char*)AloT_;
    bf16* __restrict__ Xout = isQ ? qf : kf;
    float* __restrict__ Sout = isQ ? Sq : Sk;
    const int Nd = isQ ? (NH * HD) : (NKV * HD);

    const int m0g = rb * 128;
    const int t = threadIdx.x;
    const int w = t >> 6, L = t & 63;
    const int lm = L & 15, lq = L >> 4;

    __shared__ __align__(16) char arena[34816];
    __shared__ float red[4][128];
    char* Wh_s = arena;
    char* Wl_s = arena + 8192;
    char* Ah_s = arena + 16384;
    char* Al_s = arena + 24576;

    f32x4 acc[2][8];
#pragma unroll
    for (int mt = 0; mt < 2; mt++)
#pragma unroll
        for (int nt = 0; nt < 8; nt++) acc[mt][nt] = (f32x4){0.f, 0.f, 0.f, 0.f};

    for (int kt = 0; kt < 64; kt++) {
        __syncthreads();
        const size_t tW = (size_t)kt * 8192;
#pragma unroll
        for (int i = 0; i < 2; i++) {
            const int so = (w * 2 + i) * 1024;
            gl16(WHb + tW + so + L * 16, Wh_s + so);
            if (np3) gl16(WLb + tW + so + L * 16, Wl_s + so);
        }
        if (AHb) {
            const size_t tA = ((size_t)rb * 64 + kt) * 8192;
#pragma unroll
            for (int i = 0; i < 2; i++) {
                const int so = (w * 2 + i) * 1024;
                gl16(AHb + tA + so + L * 16, Ah_s + so);
                if (np3) gl16(ALb + tA + so + L * 16, Al_s + so);
            }
        } else {
            const int k0 = kt * 32;
#pragma unroll
            for (int i = 0; i < 2; i++) {
                const int task = t + i * 256;
                const int row = task >> 2, q2 = task & 3;
                const float* ap = &A[(size_t)(m0g + row) * HID + k0 + q2 * 8];
                const float4 v0 = *(const float4*)ap;
                const float4 v1 = *(const float4*)(ap + 4);
                const float f[8] = {v0.x, v0.y, v0.z, v0.w, v1.x, v1.y, v1.z, v1.w};
                alignas(16) unsigned short hh[8], lo[8];
#pragma unroll
                for (int j = 0; j < 8; j++) {
                    hh[j] = f2b(f[j]);
                    if (np3) lo[j] = f2b(f[j] - b2f(hh[j]));
                }
                const int ch = ((row * 4 + q2) ^ (row & 7)) * 16;
                *(uint4*)(Ah_s + ch) = *(const uint4*)hh;
                if (np3) *(uint4*)(Al_s + ch) = *(const uint4*)lo;
            }
        }
        __syncthreads();
        const int xr = lm & 7;
        short8 ah[2], al[2];
#pragma unroll
        for (int mt = 0; mt < 2; mt++) {
            const int rowA = w * 32 + mt * 16 + lm;
            const int cA = (((rowA * 4 + lq) ^ xr)) * 16;
            ah[mt] = *(const short8*)(Ah_s + cA);
            if (np3) al[mt] = *(const short8*)(Al_s + cA);
        }
#pragma unroll
        for (int nt = 0; nt < 8; nt++) {
            const int rowW = nt * 16 + lm;
            const int cW = (((rowW * 4 + lq) ^ xr)) * 16;
            const short8 bh = *(const short8*)(Wh_s + cW);
#pragma unroll
            for (int mt = 0; mt < 2; mt++)
                acc[mt][nt] = __builtin_amdgcn_mfma_f32_16x16x32_bf16(ah[mt], bh, acc[mt][nt], 0, 0, 0);
            if (np3) {
                const short8 bl = *(const short8*)(Wl_s + cW);
#pragma unroll
                for (int mt = 0; mt < 2; mt++) {
                    acc[mt][nt] = __builtin_amdgcn_mfma_f32_16x16x32_bf16(ah[mt], bl, acc[mt][nt], 0, 0, 0);
                    acc[mt][nt] = __builtin_amdgcn_mfma_f32_16x16x32_bf16(al[mt], bh, acc[mt][nt], 0, 0, 0);
                }
            }
        }
    }

    if (isV) {
        __syncthreads();
        unsigned short(*Tv)[136] = (unsigned short(*)[136])arena;
#pragma unroll
        for (int mt = 0; mt < 2; mt++) {
            const int rbs = w * 32 + mt * 16 + lq * 4;
#pragma unroll
            for (int rr = 0; rr < 4; rr++)
#pragma unroll
                for (int nt = 0; nt < 8; nt++)
                    Tv[nt * 16 + lm][rbs + rr] = f2b(acc[mt][nt][rr]);
        }
        __syncthreads();
        const int col = t >> 1, rh = (t & 1) * 64;
        bf16* dst = &vfT[((size_t)h * HD + col) * S_LEN + m0g + rh];
#pragma unroll
        for (int u2 = 0; u2 < 8; u2++)
            *(uint4*)&dst[u2 * 8] = *(const uint4*)&Tv[col][rh + u2 * 8];
        return;
    }

    {
        float invf[4];
#pragma unroll
        for (int c4 = 0; c4 < 4; c4++) {
            const int jj = c4 * 16 + lm;
            invf[c4] = 1.0f / powf(10000.0f, (float)jj * (1.0f / 64.0f));
        }
#pragma unroll
        for (int mt = 0; mt < 2; mt++) {
            const int rbase = w * 32 + mt * 16 + lq * 4;
#pragma unroll
            for (int rr = 0; rr < 4; rr++) {
                const float p = (float)pos_ids[m0g + rbase + rr];
#pragma unroll
                for (int c4 = 0; c4 < 4; c4++) {
                    const float fr = p * invf[c4];
                    float sv, cv;
                    sincosf(fr, &sv, &cv);
                    const float x1 = acc[mt][c4][rr];
                    const float x2 = acc[mt][c4 + 4][rr];
                    acc[mt][c4][rr]     = x1 * cv - x2 * sv;
                    acc[mt][c4 + 4][rr] = x2 * cv + x1 * sv;
                }
            }
        }
    }

    float cs[8];
#pragma unroll
    for (int nt = 0; nt < 8; nt++) cs[nt] = 0.f;
#pragma unroll
    for (int mt = 0; mt < 2; mt++) {
        const int rbase = w * 32 + mt * 16 + lq * 4;
#pragma unroll
        for (int rr = 0; rr < 4; rr++) {
            bf16* dst = &Xout[(size_t)(m0g + rbase + rr) * Nd + h * HD + lm];
#pragma unroll
            for (int nt = 0; nt < 8; nt++) {
                const float v = acc[mt][nt][rr];
                dst[nt * 16] = __float2bfloat16(v);
                cs[nt] += v;
            }
        }
    }
#pragma unroll
    for (int nt = 0; nt < 8; nt++) {
        cs[nt] += __shfl_xor(cs[nt], 16);
        cs[nt] += __shfl_xor(cs[nt], 32);
    }
    if (lq == 0) {
#pragma unroll
        for (int nt = 0; nt < 8; nt++) red[w][nt * 16 + lm] = cs[nt];
    }
    __syncthreads();
    if (t < 64) {
        const int b = t >> 5, m = t & 31;
        float s = 0.f;
        for (int d = 0; d < 128; d++)
            s += (red[b * 2][d] + red[b * 2 + 1][d]) * H[d * MSK + m];
        Sout[((size_t)h * NBLK + (m0g >> 6) + b) * MSK + m] = s * (1.0f / 64.0f);
    }
}

// ---------------------------------------------------------------------------
// R12 fused projection (inline W split, raw fp32 W) -- small-ws tiers.
// ---------------------------------------------------------------------------
__global__ __launch_bounds__(256, 3) void proj_rope_sketch(
    const float* __restrict__ A, const float* __restrict__ Wq,
    const float* __restrict__ Wk, const float* __restrict__ Wv,
    const int* __restrict__ pos_ids, const float* __restrict__ H,
    bf16* __restrict__ qf, bf16* __restrict__ kf, bf16* __restrict__ vf,
    float* __restrict__ Sq, float* __restrict__ Sk,
    int u0, int r0, int xbase) {
    const int u = blockIdx.x + u0;
    const bool isQ = (u < 16);
    const bool isV = (u >= 20);
    const bool np3 = !isV;
    const int h = isQ ? u : (isV ? (u - 20) : (u - 16));
    const float* __restrict__ W = isQ ? Wq : (isV ? Wv : Wk);
    const int Nd = isQ ? (NH * HD) : (NKV * HD);
    bf16* __restrict__ Xout = isQ ? qf : kf;
    float* __restrict__ Sout = isQ ? Sq : Sk;

    const int m0g = r0 + blockIdx.y * 128;
    const int m0x = isQ ? (m0g - xbase) : m0g;
    const int t = threadIdx.x;
    const int w = t >> 6, L = t & 63;
    const int lm = L & 15, lq = L >> 4;

    __shared__ __align__(16) unsigned short shmem[4 * 128 * 40];
    __shared__ float red[4][128];
    unsigned short(*pAh)[40] = (unsigned short(*)[40])(shmem);
    unsigned short(*pAl)[40] = (unsigned short(*)[40])(shmem + 128 * 40);
    unsigned short(*pWh)[40] = (unsigned short(*)[40])(shmem + 2 * 128 * 40);
    unsigned short(*pWl)[40] = (unsigned short(*)[40])(shmem + 3 * 128 * 40);

    f32x4 acc[2][8];
#pragma unroll
    for (int mt = 0; mt < 2; mt++)
#pragma unroll
        for (int nt = 0; nt < 8; nt++) acc[mt][nt] = (f32x4){0.f, 0.f, 0.f, 0.f};

    for (int k0 = 0; k0 < HID; k0 += 32) {
        __syncthreads();
#pragma unroll
        for (int i = 0; i < 4; i++) {
            const int idx = t + i * 256;
            const int row = idx >> 3, f4 = idx & 7;
            const float4 v = *(const float4*)&A[(size_t)(m0g + row) * HID + k0 + f4 * 4];
            ushort4 uh;
            uh.x = f2b(v.x); uh.y = f2b(v.y); uh.z = f2b(v.z); uh.w = f2b(v.w);
            *(ushort4*)&pAh[row][f4 * 4] = uh;
            if (np3) {
                ushort4 ul;
                ul.x = f2b(v.x - b2f(uh.x)); ul.y = f2b(v.y - b2f(uh.y));
                ul.z = f2b(v.z - b2f(uh.z)); ul.w = f2b(v.w - b2f(uh.w));
                *(ushort4*)&pAl[row][f4 * 4] = ul;
            }
        }
        {
            const int wcol = t >> 1, wk0 = (t & 1) * 16;
            const float* wp = &W[(size_t)(k0 + wk0) * Nd + h * HD + wcol];
            alignas(16) unsigned short hh[16];
            alignas(16) unsigned short ll[16];
#pragma unroll
            for (int uu = 0; uu < 16; uu++) {
                const float x = wp[(size_t)uu * Nd];
                hh[uu] = f2b(x);
                ll[uu] = f2b(x - b2f(hh[uu]));
            }
            *(uint4*)&pWh[wcol][wk0 + 0] = *(const uint4*)&hh[0];
            *(uint4*)&pWh[wcol][wk0 + 8] = *(const uint4*)&hh[8];
            if (np3) {
                *(uint4*)&pWl[wcol][wk0 + 0] = *(const uint4*)&ll[0];
                *(uint4*)&pWl[wcol][wk0 + 8] = *(const uint4*)&ll[8];
            }
        }
        __syncthreads();
        short8 ah[2], al[2];
#pragma unroll
        for (int mt = 0; mt < 2; mt++) {
            ah[mt] = *(const short8*)&pAh[w * 32 + mt * 16 + lm][lq * 8];
            if (np3) al[mt] = *(const short8*)&pAl[w * 32 + mt * 16 + lm][lq * 8];
        }
#pragma unroll
        for (int nt = 0; nt < 8; nt++) {
            const short8 bh = *(const short8*)&pWh[nt * 16 + lm][lq * 8];
#pragma unroll
            for (int mt = 0; mt < 2; mt++)
                acc[mt][nt] = __builtin_amdgcn_mfma_f32_16x16x32_bf16(ah[mt], bh, acc[mt][nt], 0, 0, 0);
            if (np3) {
                const short8 bl = *(const short8*)&pWl[nt * 16 + lm][lq * 8];
#pragma unroll
                for (int mt = 0; mt < 2; mt++) {
                    acc[mt][nt] = __builtin_amdgcn_mfma_f32_16x16x32_bf16(ah[mt], bl, acc[mt][nt], 0, 0, 0);
                    acc[mt][nt] = __builtin_amdgcn_mfma_f32_16x16x32_bf16(al[mt], bh, acc[mt][nt], 0, 0, 0);
                }
            }
        }
    }

    if (isV) {
        __syncthreads();
        unsigned short(*Tv)[136] = (unsigned short(*)[136])shmem;
#pragma unroll
        for (int mt = 0; mt < 2; mt++) {
            const int rbs = w * 32 + mt * 16 + lq * 4;
#pragma unroll
            for (int rr = 0; rr < 4; rr++)
#pragma unroll
                for (int nt = 0; nt < 8; nt++)
                    Tv[nt * 16 + lm][rbs + rr] = f2b(acc[mt][nt][rr]);
        }
        __syncthreads();
        const int col = t >> 1, rh = (t & 1) * 64;
        bf16* dst = &vf[((size_t)h * HD + col) * S_LEN + m0g + rh];
#pragma unroll
        for (int u2 = 0; u2 < 8; u2++)
            *(uint4*)&dst[u2 * 8] = *(const uint4*)&Tv[col][rh + u2 * 8];
        return;
    }

    {
        float invf[4];
#pragma unroll
        for (int c4 = 0; c4 < 4; c4++) {
            const int jj = c4 * 16 + lm;
            invf[c4] = 1.0f / powf(10000.0f, (float)jj * (1.0f / 64.0f));
        }
#pragma unroll
        for (int mt = 0; mt < 2; mt++) {
            const int rbase = w * 32 + mt * 16 + lq * 4;
#pragma unroll
            for (int rr = 0; rr < 4; rr++) {
                const float p = (float)pos_ids[m0g + rbase + rr];
#pragma unroll
                for (int c4 = 0; c4 < 4; c4++) {
                    const float fr = p * invf[c4];
                    float sv, cv;
                    sincosf(fr, &sv, &cv);
                    const float x1 = acc[mt][c4][rr];
                    const float x2 = acc[mt][c4 + 4][rr];
                    acc[mt][c4][rr]     = x1 * cv - x2 * sv;
                    acc[mt][c4 + 4][rr] = x2 * cv + x1 * sv;
                }
            }
        }
    }

    float cs[8];
#pragma unroll
    for (int nt = 0; nt < 8; nt++) cs[nt] = 0.f;
#pragma unroll
    for (int mt = 0; mt < 2; mt++) {
        const int rbase = w * 32 + mt * 16 + lq * 4;
#pragma unroll
        for (int rr = 0; rr < 4; rr++) {
            bf16* dst = &Xout[(size_t)(m0x + rbase + rr) * Nd + h * HD + lm];
#pragma unroll
            for (int nt = 0; nt < 8; nt++) {
                const float v = acc[mt][nt][rr];
                dst[nt * 16] = __float2bfloat16(v);
                cs[nt] += v;
            }
        }
    }
#pragma unroll
    for (int nt = 0; nt < 8; nt++) {
        cs[nt] += __shfl_xor(cs[nt], 16);
        cs[nt] += __shfl_xor(cs[nt], 32);
    }
    if (lq == 0) {
#pragma unroll
        for (int nt = 0; nt < 8; nt++) red[w][nt * 16 + lm] = cs[nt];
    }
    __syncthreads();
    if (t < 64) {
        const int b = t >> 5, m = t & 31;
        float s = 0.f;
        for (int d = 0; d < 128; d++)
            s += (red[b * 2][d] + red[b * 2 + 1][d]) * H[d * MSK + m];
        Sout[((size_t)h * NBLK + (m0g >> 6) + b) * MSK + m] = s * (1.0f / 64.0f);
    }
}

// ---------------------------------------------------------------------------
// Block scores + top-8 for q-blocks i = i0 + bx. Tie-break = lowest index.
// ---------------------------------------------------------------------------
__global__ __launch_bounds__(64) void topk_kernel(const float* __restrict__ Sq,
                                                  const float* __restrict__ Sk,
                                                  int* __restrict__ topk, int i0) {
    const int i = i0 + blockIdx.x, h = blockIdx.y, kv = h >> 2;
    const int j = threadIdx.x;
    __shared__ float vals[64];
    float v;
    if (j > i) v = NEGV;
    else if (j == i) v = 1e9f;
    else {
        v = 0.f;
        const float* sq = Sq + ((size_t)h * NBLK + i) * MSK;
        const float* sk = Sk + ((size_t)kv * NBLK + j) * MSK;
        for (int m = 0; m < MSK; m++) v += sq[m] * sk[m];
    }
    vals[j] = v;
    __syncthreads();
    if (j == 0) {
        for (int kk = 0; kk < KTOP; kk++) {
            float best = SENT; int bi = 0;
            for (int jj = 0; jj < 64; jj++)
                if (vals[jj] > best) { best = vals[jj]; bi = jj; }
            vals[bi] = SENT;
            topk[((size_t)h * NBLK + i) * KTOP + kk] = bi;
        }
    }
}

// ---------------------------------------------------------------------------
// MFMA sparse attention v2: BARRIER-FREE main loop. K/V B-fragments loaded
// per-lane DIRECTLY from global (kf row-major / vfT transposed are 16B-aligned
// at fragment addresses; 2MB per head-group = L2-resident). Only LDS use is
// the wave-private Ps pane (9KB; same-wave ds ordering, no barrier needed).
// Block = 64 q-rows x head h; 4 waves x 16 q-rows. Writes IN PLACE over qf.
// ---------------------------------------------------------------------------
__global__ __launch_bounds__(256) void attn_kernel(bf16* __restrict__ qf,
                                                   const bf16* __restrict__ kf,
                                                   const bf16* __restrict__ vfT,
                                                   const int* __restrict__ topk,
                                                   int r0, int qbase) {
    const int qbg = (r0 >> 6) + blockIdx.x;
    const int h = blockIdx.y, kvh = h >> 2;
    const int t = threadIdx.x;
    const int w = t >> 6, L = t & 63;
    const int lm = L & 15, lq = L >> 4;

    __shared__ __align__(16) unsigned short Ps[64][72];    // [qrow][kcol], wave-private rows

    short8 qfrag[4];
    {
        const size_t qrow = (size_t)(qbg * 64 - qbase) + w * 16 + lm;
        const unsigned short* qp = (const unsigned short*)qf + qrow * (NH * HD) + h * HD;
#pragma unroll
        for (int ks = 0; ks < 4; ks++)
            qfrag[ks] = *(const short8*)&qp[ks * 32 + lq * 8];
    }
    f32x4 O[8];
#pragma unroll
    for (int nt = 0; nt < 8; nt++) O[nt] = (f32x4){0.f, 0.f, 0.f, 0.f};
    f32x4 mrow = (f32x4){-1e30f, -1e30f, -1e30f, -1e30f};
    f32x4 lrow = (f32x4){0.f, 0.f, 0.f, 0.f};

    const int* sel = topk + ((size_t)h * NBLK + qbg) * KTOP;
    const int qpos0 = qbg * 64 + w * 16 + lq * 4;
    const float scale = 0.08838834764831845f;

    // per-lane fragment base offsets
    const unsigned short* kf_u  = (const unsigned short*)kf + (size_t)kvh * HD;
    const unsigned short* vfT_u = (const unsigned short*)vfT + ((size_t)kvh * HD) * S_LEN;

    for (int kb = 0; kb < KTOP; kb++) {
        const int blk = sel[kb] & 63;
        // ---- S = Q @ K^T : K B-frags direct from global (L2) ----
        const unsigned short* kb0 = kf_u + (size_t)(blk * 64) * (NKV * HD);
        f32x4 S4[4];
#pragma unroll
        for (int nt = 0; nt < 4; nt++) {
            S4[nt] = (f32x4){0.f, 0.f, 0.f, 0.f};
            const unsigned short* kr = kb0 + (size_t)(nt * 16 + lm) * (NKV * HD);
#pragma unroll
            for (int ks = 0; ks < 4; ks++) {
                const short8 bk = *(const short8*)&kr[ks * 32 + lq * 8];
                S4[nt] = __builtin_amdgcn_mfma_f32_16x16x32_bf16(qfrag[ks], bk, S4[nt], 0, 0, 0);
            }
        }
        // scale + causal mask
#pragma unroll
        for (int nt = 0; nt < 4; nt++) {
            const int kpos = blk * 64 + nt * 16 + lm;
#pragma unroll
            for (int r = 0; r < 4; r++)
                S4[nt][r] = (kpos <= qpos0 + r) ? S4[nt][r] * scale : NEGV;
        }
        // online softmax (row = lq*4+r within wave's 16 rows; reduce over lm)
        f32x4 mx = S4[0];
#pragma unroll
        for (int nt = 1; nt < 4; nt++)
#pragma unroll
            for (int r = 0; r < 4; r++) mx[r] = fmaxf(mx[r], S4[nt][r]);
#pragma unroll
        for (int d = 1; d < 16; d <<= 1)
#pragma unroll
            for (int r = 0; r < 4; r++) mx[r] = fmaxf(mx[r], __shfl_xor(mx[r], d));
        f32x4 mnew, alv, sum;
#pragma unroll
        for (int r = 0; r < 4; r++) {
            mnew[r] = fmaxf(mrow[r], mx[r]);
            alv[r] = __expf(mrow[r] - mnew[r]);
            sum[r] = 0.f;
        }
#pragma unroll
        for (int nt = 0; nt < 4; nt++)
#pragma unroll
            for (int r = 0; r < 4; r++) {
                const float p = __expf(S4[nt][r] - mnew[r]);
                S4[nt][r] = p;
                sum[r] += p;
            }
#pragma unroll
        for (int d = 1; d < 16; d <<= 1)
#pragma unroll
            for (int r = 0; r < 4; r++) sum[r] += __shfl_xor(sum[r], d);
#pragma unroll
        for (int r = 0; r < 4; r++) {
            lrow[r] = lrow[r] * alv[r] + sum[r];
            mrow[r] = mnew[r];
        }
        // P -> bf16 into wave-private Ps rows (same-wave ds ordering; no barrier)
#pragma unroll
        for (int nt = 0; nt < 4; nt++)
#pragma unroll
            for (int r = 0; r < 4; r++)
                Ps[w * 16 + lq * 4 + r][nt * 16 + lm] = f2b(S4[nt][r]);
        // O rescale + PV: V B-frags direct from vfT (transposed layout = B-frag layout)
#pragma unroll
        for (int nt = 0; nt < 8; nt++)
#pragma unroll
            for (int r = 0; r < 4; r++) O[nt][r] *= alv[r];
        const unsigned short* vb0 = vfT_u + blk * 64;
#pragma unroll
        for (int ks2 = 0; ks2 < 2; ks2++) {
            const short8 pa = *(const short8*)&Ps[w * 16 + lm][ks2 * 32 + lq * 8];
#pragma unroll
            for (int nt = 0; nt < 8; nt++) {
                const short8 vv = *(const short8*)&vb0[(size_t)(nt * 16 + lm) * S_LEN + ks2 * 32 + lq * 8];
                O[nt] = __builtin_amdgcn_mfma_f32_16x16x32_bf16(pa, vv, O[nt], 0, 0, 0);
            }
        }
    }
    f32x4 inv;
#pragma unroll
    for (int r = 0; r < 4; r++) inv[r] = 1.0f / lrow[r];
    const size_t orow0 = (size_t)(qbg * 64 - qbase) + w * 16 + lq * 4;
#pragma unroll
    for (int nt = 0; nt < 8; nt++)
#pragma unroll
        for (int r = 0; r < 4; r++)
            qf[(orow0 + r) * (NH * HD) + h * HD + nt * 16 + lm] =
                __float2bfloat16(O[nt][r] * inv[r]);
}

// ---------------------------------------------------------------------------
// Output GEMM (fp32 Wo, inline convert) -- tiers without WtoH.
// ---------------------------------------------------------------------------
__global__ __launch_bounds__(256) void gemm_out(const bf16* __restrict__ A,
                                                const float* __restrict__ W,
                                                float* __restrict__ C, int cRow0) {
    __shared__ __align__(16) unsigned short Wl[128][40];
    const int n0 = blockIdx.x * 128, m0 = blockIdx.y * 128;
    const int t = threadIdx.x;
    const int w = t >> 6, L = t & 63;
    const int lm = L & 15, lq = L >> 4;
    const int wcol = t >> 1, wk0 = (t & 1) * 16;
    f32x4 acc[2][8];
#pragma unroll
    for (int mt = 0; mt < 2; mt++)
#pragma unroll
        for (int nt = 0; nt < 8; nt++) acc[mt][nt] = (f32x4){0.f, 0.f, 0.f, 0.f};

    float wreg[16];
    {
        const float* wp = &W[(size_t)wk0 * HID + n0 + wcol];
#pragma unroll
        for (int u = 0; u < 16; u++) wreg[u] = wp[(size_t)u * HID];
    }
    short8 av[2];
#pragma unroll
    for (int mt = 0; mt < 2; mt++)
        av[mt] = *(const short8*)&A[(size_t)(m0 + w * 32 + mt * 16 + lm) * HID + lq * 8];

    for (int k0 = 0; k0 < HID; k0 += 32) {
        __syncthreads();
        {
            alignas(16) unsigned short hh[16];
#pragma unroll
            for (int u = 0; u < 16; u++) hh[u] = f2b(wreg[u]);
            *(uint4*)&Wl[wcol][wk0 + 0] = *(const uint4*)&hh[0];
            *(uint4*)&Wl[wcol][wk0 + 8] = *(const uint4*)&hh[8];
        }
        const int k1 = k0 + 32;
        if (k1 < HID) {
            const float* wp = &W[(size_t)(k1 + wk0) * HID + n0 + wcol];
#pragma unroll
            for (int u = 0; u < 16; u++) wreg[u] = wp[(size_t)u * HID];
        }
        __syncthreads();
        short8 avn[2];
        if (k1 < HID) {
#pragma unroll
            for (int mt = 0; mt < 2; mt++)
                avn[mt] = *(const short8*)&A[(size_t)(m0 + w * 32 + mt * 16 + lm) * HID + k1 + lq * 8];
        }
#pragma unroll
        for (int nt = 0; nt < 8; nt++) {
            const short8 bv = *(const short8*)&Wl[nt * 16 + lm][lq * 8];
#pragma unroll
            for (int mt = 0; mt < 2; mt++)
                acc[mt][nt] = __builtin_amdgcn_mfma_f32_16x16x32_bf16(av[mt], bv, acc[mt][nt], 0, 0, 0);
        }
        if (k1 < HID) { av[0] = avn[0]; av[1] = avn[1]; }
    }
#pragma unroll
    for (int mt = 0; mt < 2; mt++)
#pragma unroll
        for (int nt = 0; nt < 8; nt++)
#pragma unroll
            for (int r = 0; r < 4; r++) {
                const int row = m0 + w * 32 + mt * 16 + lq * 4 + r;
                C[(size_t)(cRow0 + row) * HID + n0 + nt * 16 + lm] = acc[mt][nt][r];
            }
}

// ---------------------------------------------------------------------------
// Output GEMM v2 (R15-proven): 128x128 tile, W from WtoH [n][k] bf16; BK=64;
// W register double-buffered (copy-only staging).
// ---------------------------------------------------------------------------
__global__ __launch_bounds__(256) void gemm_out2(const bf16* __restrict__ A,
                                                 const bf16* __restrict__ WtoH,
                                                 float* __restrict__ C) {
    __shared__ __align__(16) unsigned short Wl[128][72];
    const int n0 = blockIdx.x * 128, m0 = blockIdx.y * 128;
    const int t = threadIdx.x;
    const int w = t >> 6, L = t & 63;
    const int lm = L & 15, lq = L >> 4;
    const int ct = t >> 1, sg = (t & 1) * 32;
    const unsigned short* __restrict__ WT = (const unsigned short*)WtoH;
    f32x4 acc[2][8];
#pragma unroll
    for (int mt = 0; mt < 2; mt++)
#pragma unroll
        for (int nt = 0; nt < 8; nt++) acc[mt][nt] = (f32x4){0.f, 0.f, 0.f, 0.f};

    uint4 wbuf[4];
    {
        const unsigned short* wp = &WT[(size_t)(n0 + ct) * HID + sg];
#pragma unroll
        for (int i = 0; i < 4; i++) wbuf[i] = *(const uint4*)&wp[i * 8];
    }
    short8 av[2][2];
#pragma unroll
    for (int mt = 0; mt < 2; mt++)
#pragma unroll
        for (int ks = 0; ks < 2; ks++)
            av[mt][ks] = *(const short8*)&A[(size_t)(m0 + w * 32 + mt * 16 + lm) * HID + ks * 32 + lq * 8];

    for (int k0 = 0; k0 < HID; k0 += 64) {
        __syncthreads();
#pragma unroll
        for (int i = 0; i < 4; i++) *(uint4*)&Wl[ct][sg + i * 8] = wbuf[i];
        const int k1 = k0 + 64;
        if (k1 < HID) {
            const unsigned short* wp = &WT[(size_t)(n0 + ct) * HID + k1 + sg];
#pragma unroll
            for (int i = 0; i < 4; i++) wbuf[i] = *(const uint4*)&wp[i * 8];
        }
        __syncthreads();
        short8 avn[2][2];
        if (k1 < HID) {
#pragma unroll
            for (int mt = 0; mt < 2; mt++)
#pragma unroll
                for (int ks = 0; ks < 2; ks++)
                    avn[mt][ks] = *(const short8*)&A[(size_t)(m0 + w * 32 + mt * 16 + lm) * HID + k1 + ks * 32 + lq * 8];
        }
#pragma unroll
        for (int ks = 0; ks < 2; ks++)
#pragma unroll
            for (int nt = 0; nt < 8; nt++) {
                const short8 bv = *(const short8*)&Wl[nt * 16 + lm][ks * 32 + lq * 8];
#pragma unroll
                for (int mt = 0; mt < 2; mt++)
                    acc[mt][nt] = __builtin_amdgcn_mfma_f32_16x16x32_bf16(av[mt][ks], bv, acc[mt][nt], 0, 0, 0);
            }
        if (k1 < HID) {
#pragma unroll
            for (int mt = 0; mt < 2; mt++)
#pragma unroll
                for (int ks = 0; ks < 2; ks++) av[mt][ks] = avn[mt][ks];
        }
    }
#pragma unroll
    for (int mt = 0; mt < 2; mt++)
#pragma unroll
        for (int nt = 0; nt < 8; nt++)
#pragma unroll
            for (int r = 0; r < 4; r++) {
                const int row = m0 + w * 32 + mt * 16 + lq * 4 + r;
                C[(size_t)row * HID + n0 + nt * 16 + lm] = acc[mt][nt][r];
            }
}

// ---------------------------------------------------------------------------
extern "C" void kernel_launch(void* const* d_in, const int* in_sizes, int n_in,
                              void* d_out, int out_size, void* d_ws, size_t ws_size,
                              hipStream_t stream) {
    const void *p_hid, *p_pos, *p_wq, *p_wk, *p_wv, *p_wo, *p_h;
    if (in_sizes[0] == 4096 && in_sizes[1] == 1048576) {
        p_h = d_in[0]; p_wk = d_in[1]; p_wo = d_in[2]; p_wq = d_in[3];
        p_wv = d_in[4]; p_hid = d_in[5]; p_pos = d_in[6];
    } else {
        p_hid = d_in[0]; p_pos = d_in[1]; p_wq = d_in[2]; p_wk = d_in[3];
        p_wv = d_in[4]; p_wo = d_in[5]; p_h = d_in[6];
    }
    const float* hidden = (const float*)p_hid;
    const int* pos_ids  = (const int*)p_pos;
    const float* Wq = (const float*)p_wq;
    const float* Wk = (const float*)p_wk;
    const float* Wv = (const float*)p_wv;
    const float* Wo = (const float*)p_wo;
    const float* Hsk = (const float*)p_h;
    float* out = (float*)d_out;

    // ws layout (bytes):
    //  FULL : Sq 131072 | Sk 32768 | topk 32768 | kf 4M | vfT 4M | qf 16.78M = 25,362,432
    //  FULL2 adds: WtqH 8M | WtqL 8M | WtkH 2M | WtkL 2M | WtvH 2M (tiled)   = 48,431,104
    //  FULL3 adds: WtoH 8M (linear [n][k])                                   = 56,819,712
    //  FULL4 adds: AhiT 16M | AloT 16M (tiled)                               = 90,374,144
    char* base = (char*)d_ws;
    float* Sq    = (float*)base;
    float* Sk    = (float*)(base + 131072);
    int*   topkb = (int*)(base + 163840);
    bf16*  kf    = (bf16*)(base + 196608);
    bf16*  vfT   = (bf16*)(base + 196608 + 4194304);
    bf16*  qbuf  = (bf16*)(base + 196608 + 8388608);
    bf16*  WtqH  = (bf16*)(base + 25362432);
    bf16*  WtqL  = (bf16*)(base + 33751040);
    bf16*  WtkH  = (bf16*)(base + 42139648);
    bf16*  WtkL  = (bf16*)(base + 44236800);
    bf16*  WtvH  = (bf16*)(base + 46333952);
    bf16*  WtoH  = (bf16*)(base + 48431104);
    bf16*  AhiT  = (bf16*)(base + 56819712);
    bf16*  AloT  = (bf16*)(base + 73596928);
    const size_t FULL_NEED  = 25362432;
    const size_t FULL2_NEED = 48431104;
    const size_t FULL3_NEED = 56819712;
    const size_t FULL4_NEED = 90374144;

    if (ws_size >= FULL2_NEED) {
        const bool hasWo = (ws_size >= FULL3_NEED);
        const bool hasA  = (ws_size >= FULL4_NEED);
        const int nA  = hasA ? 2048 : 0;
        const int nWo = hasWo ? 1024 : 0;
        prepass<<<dim3(nA + 1536 + nWo), 256, 0, stream>>>(
            Wq, Wk, Wv, Wo, hidden,
            WtqH, WtqL, WtkH, WtkL, WtvH, WtoH, AhiT, AloT, nA);
        proj4<<<dim3(24, 32), 256, 0, stream>>>(
            hidden, hasA ? AhiT : nullptr, hasA ? AloT : nullptr,
            WtqH, WtqL, WtkH, WtkL, WtvH, pos_ids, Hsk,
            qbuf, kf, vfT, Sq, Sk);
        topk_kernel<<<dim3(NBLK, NH), 64, 0, stream>>>(Sq, Sk, topkb, 0);
        attn_kernel<<<dim3(NBLK, NH), 256, 0, stream>>>(
            qbuf, kf, vfT, topkb, 0, 0);
        if (hasWo)
            gemm_out2<<<dim3(HID / 128, S_LEN / 128), 256, 0, stream>>>(
                qbuf, WtoH, out);
        else
            gemm_out<<<dim3(HID / 128, S_LEN / 128), 256, 0, stream>>>(
                qbuf, Wo, out, 0);
    } else if (ws_size >= FULL_NEED) {
        proj_rope_sketch<<<dim3(24, S_LEN / 128), 256, 0, stream>>>(
            hidden, Wq, Wk, Wv, pos_ids, Hsk, qbuf, kf, vfT, Sq, Sk, 0, 0, 0);
        topk_kernel<<<dim3(NBLK, NH), 64, 0, stream>>>(Sq, Sk, topkb, 0);
        attn_kernel<<<dim3(NBLK, NH), 256, 0, stream>>>(
            qbuf, kf, vfT, topkb, 0, 0);
        gemm_out<<<dim3(HID / 128, S_LEN / 128), 256, 0, stream>>>(
            qbuf, Wo, out, 0);
    } else {
        proj_rope_sketch<<<dim3(8, S_LEN / 128), 256, 0, stream>>>(
            hidden, Wq, Wk, Wv, pos_ids, Hsk, qbuf, kf, vfT, Sq, Sk, 16, 0, 0);
        for (int c = 0; c < 16; c++) {
            const int r0 = c * 256;
            proj_rope_sketch<<<dim3(16, 2), 256, 0, stream>>>(
                hidden, Wq, Wk, Wv, pos_ids, Hsk, qbuf, kf, vfT, Sq, Sk, 0, r0, r0);
            topk_kernel<<<dim3(4, NH), 64, 0, stream>>>(Sq, Sk, topkb, r0 >> 6);
            attn_kernel<<<dim3(4, NH), 256, 0, stream>>>(
                qbuf, kf, vfT, topkb, r0, r0);
            gemm_out<<<dim3(HID / 128, 2), 256, 0, stream>>>(
                qbuf, Wo, out, r0);
        }
    }
}

// Round 11
// 443.817 us; speedup vs baseline: 1.1810x; 1.1810x over previous
//
#include <hip/hip_runtime.h>
#include <hip/hip_bf16.h>

// Problem constants (B=1)
#define S_LEN 4096
#define HID 2048
#define NH 16
#define NKV 4
#define HD 128        // D
#define MSK 32        // M (sketch dim)
#define KTOP 8
#define NBLK 64       // S/BLK
#define NEGV -1000000000.0f
#define SENT -3.0e38f

typedef __hip_bfloat16 bf16;
typedef __attribute__((ext_vector_type(8))) short short8;   // 8 bf16 (4 VGPR)
typedef __attribute__((ext_vector_type(4))) float f32x4;

// EMPIRICAL (R1-R20): Selection needs bf16x3 (hi*hi+hi*lo+lo*hi, fp32 accum);
// V plain bf16. Proj MUST keep >=3 blocks/CU residency (R13 lesson).
// R15 (PROVEN): swizzled 8KB tile images + global_load_lds staging.
// R16 LESSON: XCD swizzle grouping units per XCD HURT. R17 LESSON: attn T14
// reg prefetch REGRESSED (VGPR spill). R19 LESSON: dropping attn's KV LDS
// staging REGRESSED +69us -- per-lane direct fragment loads are UNCOALESCED
// (64x16B scattered over 64KB per wave, 4x re-read); the LDS stage IS the
// coalescing mechanism. R20 = R18 attn (LDS-staged, proven) + topk FUSED
// into attn entry (same (qbg,h) index space; wave-0 shfl argmax, identical
// tie-break) -- deletes one launch + gap.

__device__ __forceinline__ unsigned short f2b(float v) {
    __hip_bfloat16 h = __float2bfloat16(v);
    return *reinterpret_cast<unsigned short*>(&h);
}
__device__ __forceinline__ float b2f(unsigned short u) {
    return __bfloat162float(*reinterpret_cast<__hip_bfloat16*>(&u));
}
__device__ __forceinline__ void gl16(const void* g, void* l) {
    __builtin_amdgcn_global_load_lds(
        (const __attribute__((address_space(1))) void*)g,
        (__attribute__((address_space(3))) void*)l, 16, 0, 0);
}

// ---------------------------------------------------------------------------
// MERGED pre-pass (one launch):
//  blocks [0, nA)          : hidden A -> tiled/swizzled hi+lo 8KB images
//  blocks [nA, nA+1536)    : W Q/K/V -> per-head 64 swizzled 8KB k-tiles
//  blocks [nA+1536, +nWo)  : Wo -> bf16 hi, transposed linear [n][k]
// Tile image format: [128 rows][32 k] bf16, chunk(row,lq)=((row*4+lq)^(row&7)),
// each chunk = 16B of 8 consecutive k shorts.
// ---------------------------------------------------------------------------
__global__ __launch_bounds__(256) void prepass(
    const float* __restrict__ Wq, const float* __restrict__ Wk,
    const float* __restrict__ Wv, const float* __restrict__ Wo,
    const float* __restrict__ A,
    bf16* __restrict__ WtqH, bf16* __restrict__ WtqL,
    bf16* __restrict__ WtkH, bf16* __restrict__ WtkL,
    bf16* __restrict__ WtvH, bf16* __restrict__ WtoH,
    bf16* __restrict__ AhiT, bf16* __restrict__ AloT,
    int nA) {
    __shared__ __align__(16) float LsArena[64 * 68];   // 17408B, both W shapes fit
    const int t = threadIdx.x;
    int bx = blockIdx.x;

    if (bx < nA) {        // ---- A tiles ----
        const int rb = bx >> 6, kt = bx & 63;
        char* DH = (char*)AhiT + ((size_t)rb * 64 + kt) * 8192;
        char* DL = (char*)AloT + ((size_t)rb * 64 + kt) * 8192;
#pragma unroll
        for (int i = 0; i < 2; i++) {
            const int task = t + i * 256;
            const int row = task >> 2, lq = task & 3;
            const float* ap = &A[(size_t)(rb * 128 + row) * HID + kt * 32 + lq * 8];
            const float4 v0 = *(const float4*)ap;
            const float4 v1 = *(const float4*)(ap + 4);
            const float f[8] = {v0.x, v0.y, v0.z, v0.w, v1.x, v1.y, v1.z, v1.w};
            alignas(16) unsigned short hh[8], lo[8];
#pragma unroll
            for (int j = 0; j < 8; j++) {
                hh[j] = f2b(f[j]);
                lo[j] = f2b(f[j] - b2f(hh[j]));
            }
            const size_t off = (size_t)(((row * 4 + lq) ^ (row & 7))) * 16;
            *(uint4*)(DH + off) = *(const uint4*)hh;
            *(uint4*)(DL + off) = *(const uint4*)lo;
        }
        return;
    }
    bx -= nA;

    if (bx < 1536) {      // ---- W Q/K/V tiles ----
        const int u = bx >> 6, kt = bx & 63, k0 = kt * 32;
        const float* W; char* TH; char* TL; int Nd, n0; bool hasLo;
        if (u < 16)      { W = Wq; TH = (char*)WtqH + (size_t)u * 524288;        TL = (char*)WtqL + (size_t)u * 524288; Nd = 2048; n0 = u * 128; hasLo = true; }
        else if (u < 20) { W = Wk; TH = (char*)WtkH + (size_t)(u - 16) * 524288; TL = (char*)WtkL + (size_t)(u - 16) * 524288; Nd = 512; n0 = (u - 16) * 128; hasLo = true; }
        else             { W = Wv; TH = (char*)WtvH + (size_t)(u - 20) * 524288; TL = nullptr; Nd = 512; n0 = (u - 20) * 128; hasLo = false; }
        float(*Lw)[132] = (float(*)[132])LsArena;
#pragma unroll
        for (int i = 0; i < 4; i++) {            // 32k x 128n fp32, coalesced
            const int task = t + i * 256;
            const int k = task >> 5, c4 = task & 31;
            *(float4*)&Lw[k][c4 * 4] = *(const float4*)&W[(size_t)(k0 + k) * Nd + n0 + c4 * 4];
        }
        __syncthreads();
#pragma unroll
        for (int i = 0; i < 2; i++) {            // 512 chunks
            const int task = t + i * 256;
            const int col = task >> 2, lq = task & 3;
            alignas(16) unsigned short hh[8], lo[8];
#pragma unroll
            for (int j = 0; j < 8; j++) {
                const float x = Lw[lq * 8 + j][col];
                hh[j] = f2b(x);
                lo[j] = f2b(x - b2f(hh[j]));
            }
            const size_t off = (size_t)kt * 8192 + (size_t)(((col * 4 + lq) ^ (col & 7))) * 16;
            *(uint4*)(TH + off) = *(const uint4*)hh;
            if (hasLo) *(uint4*)(TL + off) = *(const uint4*)lo;
        }
        return;
    }
    bx -= 1536;

    {                     // ---- Wo transpose ----
        const int n0 = (bx >> 5) * 64, k0 = (bx & 31) * 64;
        float(*Ls)[68] = (float(*)[68])LsArena;
        {
            const int kk = t >> 2, c0 = (t & 3) * 16;
#pragma unroll
            for (int i = 0; i < 4; i++)
                *(float4*)&Ls[kk][c0 + i * 4] =
                    *(const float4*)&Wo[(size_t)(k0 + kk) * HID + n0 + c0 + i * 4];
        }
        __syncthreads();
        const int c = t >> 2, ks = (t & 3) * 16;
        alignas(16) unsigned short hh[16];
#pragma unroll
        for (int j = 0; j < 16; j++) hh[j] = f2b(Ls[ks + j][c]);
        unsigned short* TH = (unsigned short*)WtoH;
        const size_t db = (size_t)(n0 + c) * HID + k0 + ks;
        *(uint4*)&TH[db + 0] = *(const uint4*)&hh[0];
        *(uint4*)&TH[db + 8] = *(const uint4*)&hh[8];
    }
}

// ---------------------------------------------------------------------------
// proj4: Q/K/V projection + RoPE + sketch. 2D grid (24 units, 32 row-blocks),
// DEFAULT dispatch order (R16 lesson). Staging via global_load_lds from
// swizzled tile images; frag ds_read applies the XOR.
// ---------------------------------------------------------------------------
__global__ __launch_bounds__(256, 3) void proj4(
    const float* __restrict__ A,
    const bf16* __restrict__ AhiT_, const bf16* __restrict__ AloT_,
    const bf16* __restrict__ WtqH_, const bf16* __restrict__ WtqL_,
    const bf16* __restrict__ WtkH_, const bf16* __restrict__ WtkL_,
    const bf16* __restrict__ WtvH_,
    const int* __restrict__ pos_ids, const float* __restrict__ H,
    bf16* __restrict__ qf, bf16* __restrict__ kf, bf16* __restrict__ vfT,
    float* __restrict__ Sq, float* __restrict__ Sk) {
    const int u = blockIdx.x;
    const int rb = blockIdx.y;
    const bool isQ = (u < 16);
    const bool isV = (u >= 20);
    const bool np3 = !isV;
    const int h = isQ ? u : (isV ? (u - 20) : (u - 16));
    const char* WHb = (const char*)(isQ ? WtqH_ : (isV ? WtvH_ : WtkH_)) + (size_t)h * 524288;
    const char* WLb = (const char*)(isQ ? WtqL_ : WtkL_) + (size_t)h * 524288; // not deref'd for V
    const char* AHb = (const char*)AhiT_;
    const char* ALb = (const char*)AloT_;
    bf16* __restrict__ Xout = isQ ? qf : kf;
    float* __restrict__ Sout = isQ ? Sq : Sk;
    const int Nd = isQ ? (NH * HD) : (NKV * HD);

    const int m0g = rb * 128;
    const int t = threadIdx.x;
    const int w = t >> 6, L = t & 63;
    const int lm = L & 15, lq = L >> 4;

    __shared__ __align__(16) char arena[34816];
    __shared__ float red[4][128];
    char* Wh_s = arena;
    char* Wl_s = arena + 8192;
    char* Ah_s = arena + 16384;
    char* Al_s = arena + 24576;

    f32x4 acc[2][8];
#pragma unroll
    for (int mt = 0; mt < 2; mt++)
#pragma unroll
        for (int nt = 0; nt < 8; nt++) acc[mt][nt] = (f32x4){0.f, 0.f, 0.f, 0.f};

    for (int kt = 0; kt < 64; kt++) {
        __syncthreads();
        const size_t tW = (size_t)kt * 8192;
#pragma unroll
        for (int i = 0; i < 2; i++) {
            const int so = (w * 2 + i) * 1024;
            gl16(WHb + tW + so + L * 16, Wh_s + so);
            if (np3) gl16(WLb + tW + so + L * 16, Wl_s + so);
        }
        if (AHb) {
            const size_t tA = ((size_t)rb * 64 + kt) * 8192;
#pragma unroll
            for (int i = 0; i < 2; i++) {
                const int so = (w * 2 + i) * 1024;
                gl16(AHb + tA + so + L * 16, Ah_s + so);
                if (np3) gl16(ALb + tA + so + L * 16, Al_s + so);
            }
        } else {
            const int k0 = kt * 32;
#pragma unroll
            for (int i = 0; i < 2; i++) {
                const int task = t + i * 256;
                const int row = task >> 2, q2 = task & 3;
                const float* ap = &A[(size_t)(m0g + row) * HID + k0 + q2 * 8];
                const float4 v0 = *(const float4*)ap;
                const float4 v1 = *(const float4*)(ap + 4);
                const float f[8] = {v0.x, v0.y, v0.z, v0.w, v1.x, v1.y, v1.z, v1.w};
                alignas(16) unsigned short hh[8], lo[8];
#pragma unroll
                for (int j = 0; j < 8; j++) {
                    hh[j] = f2b(f[j]);
                    if (np3) lo[j] = f2b(f[j] - b2f(hh[j]));
                }
                const int ch = ((row * 4 + q2) ^ (row & 7)) * 16;
                *(uint4*)(Ah_s + ch) = *(const uint4*)hh;
                if (np3) *(uint4*)(Al_s + ch) = *(const uint4*)lo;
            }
        }
        __syncthreads();
        const int xr = lm & 7;
        short8 ah[2], al[2];
#pragma unroll
        for (int mt = 0; mt < 2; mt++) {
            const int rowA = w * 32 + mt * 16 + lm;
            const int cA = (((rowA * 4 + lq) ^ xr)) * 16;
            ah[mt] = *(const short8*)(Ah_s + cA);
            if (np3) al[mt] = *(const short8*)(Al_s + cA);
        }
#pragma unroll
        for (int nt = 0; nt < 8; nt++) {
            const int rowW = nt * 16 + lm;
            const int cW = (((rowW * 4 + lq) ^ xr)) * 16;
            const short8 bh = *(const short8*)(Wh_s + cW);
#pragma unroll
            for (int mt = 0; mt < 2; mt++)
                acc[mt][nt] = __builtin_amdgcn_mfma_f32_16x16x32_bf16(ah[mt], bh, acc[mt][nt], 0, 0, 0);
            if (np3) {
                const short8 bl = *(const short8*)(Wl_s + cW);
#pragma unroll
                for (int mt = 0; mt < 2; mt++) {
                    acc[mt][nt] = __builtin_amdgcn_mfma_f32_16x16x32_bf16(ah[mt], bl, acc[mt][nt], 0, 0, 0);
                    acc[mt][nt] = __builtin_amdgcn_mfma_f32_16x16x32_bf16(al[mt], bh, acc[mt][nt], 0, 0, 0);
                }
            }
        }
    }

    if (isV) {
        __syncthreads();
        unsigned short(*Tv)[136] = (unsigned short(*)[136])arena;
#pragma unroll
        for (int mt = 0; mt < 2; mt++) {
            const int rbs = w * 32 + mt * 16 + lq * 4;
#pragma unroll
            for (int rr = 0; rr < 4; rr++)
#pragma unroll
                for (int nt = 0; nt < 8; nt++)
                    Tv[nt * 16 + lm][rbs + rr] = f2b(acc[mt][nt][rr]);
        }
        __syncthreads();
        const int col = t >> 1, rh = (t & 1) * 64;
        bf16* dst = &vfT[((size_t)h * HD + col) * S_LEN + m0g + rh];
#pragma unroll
        for (int u2 = 0; u2 < 8; u2++)
            *(uint4*)&dst[u2 * 8] = *(const uint4*)&Tv[col][rh + u2 * 8];
        return;
    }

    {
        float invf[4];
#pragma unroll
        for (int c4 = 0; c4 < 4; c4++) {
            const int jj = c4 * 16 + lm;
            invf[c4] = 1.0f / powf(10000.0f, (float)jj * (1.0f / 64.0f));
        }
#pragma unroll
        for (int mt = 0; mt < 2; mt++) {
            const int rbase = w * 32 + mt * 16 + lq * 4;
#pragma unroll
            for (int rr = 0; rr < 4; rr++) {
                const float p = (float)pos_ids[m0g + rbase + rr];
#pragma unroll
                for (int c4 = 0; c4 < 4; c4++) {
                    const float fr = p * invf[c4];
                    float sv, cv;
                    sincosf(fr, &sv, &cv);
                    const float x1 = acc[mt][c4][rr];
                    const float x2 = acc[mt][c4 + 4][rr];
                    acc[mt][c4][rr]     = x1 * cv - x2 * sv;
                    acc[mt][c4 + 4][rr] = x2 * cv + x1 * sv;
                }
            }
        }
    }

    float cs[8];
#pragma unroll
    for (int nt = 0; nt < 8; nt++) cs[nt] = 0.f;
#pragma unroll
    for (int mt = 0; mt < 2; mt++) {
        const int rbase = w * 32 + mt * 16 + lq * 4;
#pragma unroll
        for (int rr = 0; rr < 4; rr++) {
            bf16* dst = &Xout[(size_t)(m0g + rbase + rr) * Nd + h * HD + lm];
#pragma unroll
            for (int nt = 0; nt < 8; nt++) {
                const float v = acc[mt][nt][rr];
                dst[nt * 16] = __float2bfloat16(v);
                cs[nt] += v;
            }
        }
    }
#pragma unroll
    for (int nt = 0; nt < 8; nt++) {
        cs[nt] += __shfl_xor(cs[nt], 16);
        cs[nt] += __shfl_xor(cs[nt], 32);
    }
    if (lq == 0) {
#pragma unroll
        for (int nt = 0; nt < 8; nt++) red[w][nt * 16 + lm] = cs[nt];
    }
    __syncthreads();
    if (t < 64) {
        const int b = t >> 5, m = t & 31;
        float s = 0.f;
        for (int d = 0; d < 128; d++)
            s += (red[b * 2][d] + red[b * 2 + 1][d]) * H[d * MSK + m];
        Sout[((size_t)h * NBLK + (m0g >> 6) + b) * MSK + m] = s * (1.0f / 64.0f);
    }
}

// ---------------------------------------------------------------------------
// R12 fused projection (inline W split, raw fp32 W) -- small-ws tiers.
// ---------------------------------------------------------------------------
__global__ __launch_bounds__(256, 3) void proj_rope_sketch(
    const float* __restrict__ A, const float* __restrict__ Wq,
    const float* __restrict__ Wk, const float* __restrict__ Wv,
    const int* __restrict__ pos_ids, const float* __restrict__ H,
    bf16* __restrict__ qf, bf16* __restrict__ kf, bf16* __restrict__ vf,
    float* __restrict__ Sq, float* __restrict__ Sk,
    int u0, int r0, int xbase) {
    const int u = blockIdx.x + u0;
    const bool isQ = (u < 16);
    const bool isV = (u >= 20);
    const bool np3 = !isV;
    const int h = isQ ? u : (isV ? (u - 20) : (u - 16));
    const float* __restrict__ W = isQ ? Wq : (isV ? Wv : Wk);
    const int Nd = isQ ? (NH * HD) : (NKV * HD);
    bf16* __restrict__ Xout = isQ ? qf : kf;
    float* __restrict__ Sout = isQ ? Sq : Sk;

    const int m0g = r0 + blockIdx.y * 128;
    const int m0x = isQ ? (m0g - xbase) : m0g;
    const int t = threadIdx.x;
    const int w = t >> 6, L = t & 63;
    const int lm = L & 15, lq = L >> 4;

    __shared__ __align__(16) unsigned short shmem[4 * 128 * 40];
    __shared__ float red[4][128];
    unsigned short(*pAh)[40] = (unsigned short(*)[40])(shmem);
    unsigned short(*pAl)[40] = (unsigned short(*)[40])(shmem + 128 * 40);
    unsigned short(*pWh)[40] = (unsigned short(*)[40])(shmem + 2 * 128 * 40);
    unsigned short(*pWl)[40] = (unsigned short(*)[40])(shmem + 3 * 128 * 40);

    f32x4 acc[2][8];
#pragma unroll
    for (int mt = 0; mt < 2; mt++)
#pragma unroll
        for (int nt = 0; nt < 8; nt++) acc[mt][nt] = (f32x4){0.f, 0.f, 0.f, 0.f};

    for (int k0 = 0; k0 < HID; k0 += 32) {
        __syncthreads();
#pragma unroll
        for (int i = 0; i < 4; i++) {
            const int idx = t + i * 256;
            const int row = idx >> 3, f4 = idx & 7;
            const float4 v = *(const float4*)&A[(size_t)(m0g + row) * HID + k0 + f4 * 4];
            ushort4 uh;
            uh.x = f2b(v.x); uh.y = f2b(v.y); uh.z = f2b(v.z); uh.w = f2b(v.w);
            *(ushort4*)&pAh[row][f4 * 4] = uh;
            if (np3) {
                ushort4 ul;
                ul.x = f2b(v.x - b2f(uh.x)); ul.y = f2b(v.y - b2f(uh.y));
                ul.z = f2b(v.z - b2f(uh.z)); ul.w = f2b(v.w - b2f(uh.w));
                *(ushort4*)&pAl[row][f4 * 4] = ul;
            }
        }
        {
            const int wcol = t >> 1, wk0 = (t & 1) * 16;
            const float* wp = &W[(size_t)(k0 + wk0) * Nd + h * HD + wcol];
            alignas(16) unsigned short hh[16];
            alignas(16) unsigned short ll[16];
#pragma unroll
            for (int uu = 0; uu < 16; uu++) {
                const float x = wp[(size_t)uu * Nd];
                hh[uu] = f2b(x);
                ll[uu] = f2b(x - b2f(hh[uu]));
            }
            *(uint4*)&pWh[wcol][wk0 + 0] = *(const uint4*)&hh[0];
            *(uint4*)&pWh[wcol][wk0 + 8] = *(const uint4*)&hh[8];
            if (np3) {
                *(uint4*)&pWl[wcol][wk0 + 0] = *(const uint4*)&ll[0];
                *(uint4*)&pWl[wcol][wk0 + 8] = *(const uint4*)&ll[8];
            }
        }
        __syncthreads();
        short8 ah[2], al[2];
#pragma unroll
        for (int mt = 0; mt < 2; mt++) {
            ah[mt] = *(const short8*)&pAh[w * 32 + mt * 16 + lm][lq * 8];
            if (np3) al[mt] = *(const short8*)&pAl[w * 32 + mt * 16 + lm][lq * 8];
        }
#pragma unroll
        for (int nt = 0; nt < 8; nt++) {
            const short8 bh = *(const short8*)&pWh[nt * 16 + lm][lq * 8];
#pragma unroll
            for (int mt = 0; mt < 2; mt++)
                acc[mt][nt] = __builtin_amdgcn_mfma_f32_16x16x32_bf16(ah[mt], bh, acc[mt][nt], 0, 0, 0);
            if (np3) {
                const short8 bl = *(const short8*)&pWl[nt * 16 + lm][lq * 8];
#pragma unroll
                for (int mt = 0; mt < 2; mt++) {
                    acc[mt][nt] = __builtin_amdgcn_mfma_f32_16x16x32_bf16(ah[mt], bl, acc[mt][nt], 0, 0, 0);
                    acc[mt][nt] = __builtin_amdgcn_mfma_f32_16x16x32_bf16(al[mt], bh, acc[mt][nt], 0, 0, 0);
                }
            }
        }
    }

    if (isV) {
        __syncthreads();
        unsigned short(*Tv)[136] = (unsigned short(*)[136])shmem;
#pragma unroll
        for (int mt = 0; mt < 2; mt++) {
            const int rbs = w * 32 + mt * 16 + lq * 4;
#pragma unroll
            for (int rr = 0; rr < 4; rr++)
#pragma unroll
                for (int nt = 0; nt < 8; nt++)
                    Tv[nt * 16 + lm][rbs + rr] = f2b(acc[mt][nt][rr]);
        }
        __syncthreads();
        const int col = t >> 1, rh = (t & 1) * 64;
        bf16* dst = &vf[((size_t)h * HD + col) * S_LEN + m0g + rh];
#pragma unroll
        for (int u2 = 0; u2 < 8; u2++)
            *(uint4*)&dst[u2 * 8] = *(const uint4*)&Tv[col][rh + u2 * 8];
        return;
    }

    {
        float invf[4];
#pragma unroll
        for (int c4 = 0; c4 < 4; c4++) {
            const int jj = c4 * 16 + lm;
            invf[c4] = 1.0f / powf(10000.0f, (float)jj * (1.0f / 64.0f));
        }
#pragma unroll
        for (int mt = 0; mt < 2; mt++) {
            const int rbase = w * 32 + mt * 16 + lq * 4;
#pragma unroll
            for (int rr = 0; rr < 4; rr++) {
                const float p = (float)pos_ids[m0g + rbase + rr];
#pragma unroll
                for (int c4 = 0; c4 < 4; c4++) {
                    const float fr = p * invf[c4];
                    float sv, cv;
                    sincosf(fr, &sv, &cv);
                    const float x1 = acc[mt][c4][rr];
                    const float x2 = acc[mt][c4 + 4][rr];
                    acc[mt][c4][rr]     = x1 * cv - x2 * sv;
                    acc[mt][c4 + 4][rr] = x2 * cv + x1 * sv;
                }
            }
        }
    }

    float cs[8];
#pragma unroll
    for (int nt = 0; nt < 8; nt++) cs[nt] = 0.f;
#pragma unroll
    for (int mt = 0; mt < 2; mt++) {
        const int rbase = w * 32 + mt * 16 + lq * 4;
#pragma unroll
        for (int rr = 0; rr < 4; rr++) {
            bf16* dst = &Xout[(size_t)(m0x + rbase + rr) * Nd + h * HD + lm];
#pragma unroll
            for (int nt = 0; nt < 8; nt++) {
                const float v = acc[mt][nt][rr];
                dst[nt * 16] = __float2bfloat16(v);
                cs[nt] += v;
            }
        }
    }
#pragma unroll
    for (int nt = 0; nt < 8; nt++) {
        cs[nt] += __shfl_xor(cs[nt], 16);
        cs[nt] += __shfl_xor(cs[nt], 32);
    }
    if (lq == 0) {
#pragma unroll
        for (int nt = 0; nt < 8; nt++) red[w][nt * 16 + lm] = cs[nt];
    }
    __syncthreads();
    if (t < 64) {
        const int b = t >> 5, m = t & 31;
        float s = 0.f;
        for (int d = 0; d < 128; d++)
            s += (red[b * 2][d] + red[b * 2 + 1][d]) * H[d * MSK + m];
        Sout[((size_t)h * NBLK + (m0g >> 6) + b) * MSK + m] = s * (1.0f / 64.0f);
    }
}

// ---------------------------------------------------------------------------
// Standalone topk (fallback tiers only). Tie-break = lowest index.
// ---------------------------------------------------------------------------
__global__ __launch_bounds__(64) void topk_kernel(const float* __restrict__ Sq,
                                                  const float* __restrict__ Sk,
                                                  int* __restrict__ topk, int i0) {
    const int i = i0 + blockIdx.x, h = blockIdx.y, kv = h >> 2;
    const int j = threadIdx.x;
    __shared__ float vals[64];
    float v;
    if (j > i) v = NEGV;
    else if (j == i) v = 1e9f;
    else {
        v = 0.f;
        const float* sq = Sq + ((size_t)h * NBLK + i) * MSK;
        const float* sk = Sk + ((size_t)kv * NBLK + j) * MSK;
        for (int m = 0; m < MSK; m++) v += sq[m] * sk[m];
    }
    vals[j] = v;
    __syncthreads();
    if (j == 0) {
        for (int kk = 0; kk < KTOP; kk++) {
            float best = SENT; int bi = 0;
            for (int jj = 0; jj < 64; jj++)
                if (vals[jj] > best) { best = vals[jj]; bi = jj; }
            vals[bi] = SENT;
            topk[((size_t)h * NBLK + i) * KTOP + kk] = bi;
        }
    }
}

// ---------------------------------------------------------------------------
// MFMA sparse attention (R18-proven staging) + FUSED topk at entry.
// If Sq != nullptr: wave 0 computes this (qbg,h)'s top-8 via shfl argmax
// (value-desc, index-asc tie-break == serial first-max scan). Else reads
// precomputed topk buffer (fallback tiers).
// Block = 64 q-rows x head h; 4 waves x 16 q-rows. Writes IN PLACE over qf.
// ---------------------------------------------------------------------------
__global__ __launch_bounds__(256) void attn_kernel(bf16* __restrict__ qf,
                                                   const bf16* __restrict__ kf,
                                                   const bf16* __restrict__ vfT,
                                                   const int* __restrict__ topk,
                                                   const float* __restrict__ Sq,
                                                   const float* __restrict__ Sk,
                                                   int r0, int qbase) {
    const int qbg = (r0 >> 6) + blockIdx.x;
    const int h = blockIdx.y, kvh = h >> 2;
    const int t = threadIdx.x;
    const int w = t >> 6, L = t & 63;
    const int lm = L & 15, lq = L >> 4;

    __shared__ __align__(16) unsigned short Ks[64][136];   // [kcol][d]
    __shared__ __align__(16) unsigned short Vt[128][72];   // [d][kcol]
    __shared__ __align__(16) unsigned short Ps[64][72];    // [qrow][kcol]
    __shared__ int selS[KTOP];

    // ---- fused top-8 selection (wave 0) ----
    if (Sq != nullptr) {
        if (w == 0) {
            const int j = L;
            float v;
            if (j > qbg) v = NEGV;
            else if (j == qbg) v = 1e9f;
            else {
                v = 0.f;
                const float* sq = Sq + ((size_t)h * NBLK + qbg) * MSK;
                const float* sk = Sk + ((size_t)kvh * NBLK + j) * MSK;
                for (int m = 0; m < MSK; m++) v += sq[m] * sk[m];
            }
#pragma unroll
            for (int kk = 0; kk < KTOP; kk++) {
                float bv = v; int bi = j;
#pragma unroll
                for (int d = 1; d < 64; d <<= 1) {
                    const float ov = __shfl_xor(bv, d);
                    const int oi = __shfl_xor(bi, d);
                    if (ov > bv || (ov == bv && oi < bi)) { bv = ov; bi = oi; }
                }
                if (j == bi) v = SENT;
                if (j == 0) selS[kk] = bi;
            }
        }
    } else if (t < KTOP) {
        selS[t] = topk[((size_t)h * NBLK + qbg) * KTOP + t];
    }

    short8 qfrag[4];
    {
        const size_t qrow = (size_t)(qbg * 64 - qbase) + w * 16 + lm;
        const unsigned short* qp = (const unsigned short*)qf + qrow * (NH * HD) + h * HD;
#pragma unroll
        for (int ks = 0; ks < 4; ks++)
            qfrag[ks] = *(const short8*)&qp[ks * 32 + lq * 8];
    }
    f32x4 O[8];
#pragma unroll
    for (int nt = 0; nt < 8; nt++) O[nt] = (f32x4){0.f, 0.f, 0.f, 0.f};
    f32x4 mrow = (f32x4){-1e30f, -1e30f, -1e30f, -1e30f};
    f32x4 lrow = (f32x4){0.f, 0.f, 0.f, 0.f};

    const int qpos0 = qbg * 64 + w * 16 + lq * 4;
    const float scale = 0.08838834764831845f;

    for (int kb = 0; kb < KTOP; kb++) {
        __syncthreads();   // (A) prev LDS reads done; selS visible on kb==0
        const int blk = selS[kb] & 63;
#pragma unroll
        for (int i = 0; i < 4; i++) {
            const int idx = t + i * 256;
            const int rr = idx >> 4, c8 = idx & 15;
            *(uint4*)&Ks[rr][c8 * 8] =
                *(const uint4*)&kf[(size_t)(blk * 64 + rr) * (NKV * HD) + kvh * HD + c8 * 8];
        }
#pragma unroll
        for (int i = 0; i < 4; i++) {
            const int idx = t + i * 256;
            const int dd = idx >> 3, j8 = idx & 7;
            *(uint4*)&Vt[dd][j8 * 8] =
                *(const uint4*)&vfT[((size_t)kvh * HD + dd) * S_LEN + blk * 64 + j8 * 8];
        }
        __syncthreads();   // (B)
        f32x4 S4[4];
#pragma unroll
        for (int nt = 0; nt < 4; nt++) {
            S4[nt] = (f32x4){0.f, 0.f, 0.f, 0.f};
#pragma unroll
            for (int ks = 0; ks < 4; ks++) {
                const short8 bk = *(const short8*)&Ks[nt * 16 + lm][ks * 32 + lq * 8];
                S4[nt] = __builtin_amdgcn_mfma_f32_16x16x32_bf16(qfrag[ks], bk, S4[nt], 0, 0, 0);
            }
        }
#pragma unroll
        for (int nt = 0; nt < 4; nt++) {
            const int kpos = blk * 64 + nt * 16 + lm;
#pragma unroll
            for (int r = 0; r < 4; r++)
                S4[nt][r] = (kpos <= qpos0 + r) ? S4[nt][r] * scale : NEGV;
        }
        f32x4 mx = S4[0];
#pragma unroll
        for (int nt = 1; nt < 4; nt++)
#pragma unroll
            for (int r = 0; r < 4; r++) mx[r] = fmaxf(mx[r], S4[nt][r]);
#pragma unroll
        for (int d = 1; d < 16; d <<= 1)
#pragma unroll
            for (int r = 0; r < 4; r++) mx[r] = fmaxf(mx[r], __shfl_xor(mx[r], d));
        f32x4 mnew, alv, sum;
#pragma unroll
        for (int r = 0; r < 4; r++) {
            mnew[r] = fmaxf(mrow[r], mx[r]);
            alv[r] = __expf(mrow[r] - mnew[r]);
            sum[r] = 0.f;
        }
#pragma unroll
        for (int nt = 0; nt < 4; nt++)
#pragma unroll
            for (int r = 0; r < 4; r++) {
                const float p = __expf(S4[nt][r] - mnew[r]);
                S4[nt][r] = p;
                sum[r] += p;
            }
#pragma unroll
        for (int d = 1; d < 16; d <<= 1)
#pragma unroll
            for (int r = 0; r < 4; r++) sum[r] += __shfl_xor(sum[r], d);
#pragma unroll
        for (int r = 0; r < 4; r++) {
            lrow[r] = lrow[r] * alv[r] + sum[r];
            mrow[r] = mnew[r];
        }
#pragma unroll
        for (int nt = 0; nt < 4; nt++)
#pragma unroll
            for (int r = 0; r < 4; r++)
                Ps[w * 16 + lq * 4 + r][nt * 16 + lm] = f2b(S4[nt][r]);
#pragma unroll
        for (int nt = 0; nt < 8; nt++)
#pragma unroll
            for (int r = 0; r < 4; r++) O[nt][r] *= alv[r];
#pragma unroll
        for (int ks2 = 0; ks2 < 2; ks2++) {
            const short8 pa = *(const short8*)&Ps[w * 16 + lm][ks2 * 32 + lq * 8];
#pragma unroll
            for (int nt = 0; nt < 8; nt++) {
                const short8 vv = *(const short8*)&Vt[nt * 16 + lm][ks2 * 32 + lq * 8];
                O[nt] = __builtin_amdgcn_mfma_f32_16x16x32_bf16(pa, vv, O[nt], 0, 0, 0);
            }
        }
    }
    f32x4 inv;
#pragma unroll
    for (int r = 0; r < 4; r++) inv[r] = 1.0f / lrow[r];
    const size_t orow0 = (size_t)(qbg * 64 - qbase) + w * 16 + lq * 4;
#pragma unroll
    for (int nt = 0; nt < 8; nt++)
#pragma unroll
        for (int r = 0; r < 4; r++)
            qf[(orow0 + r) * (NH * HD) + h * HD + nt * 16 + lm] =
                __float2bfloat16(O[nt][r] * inv[r]);
}

// ---------------------------------------------------------------------------
// Output GEMM (fp32 Wo, inline convert) -- tiers without WtoH.
// ---------------------------------------------------------------------------
__global__ __launch_bounds__(256) void gemm_out(const bf16* __restrict__ A,
                                                const float* __restrict__ W,
                                                float* __restrict__ C, int cRow0) {
    __shared__ __align__(16) unsigned short Wl[128][40];
    const int n0 = blockIdx.x * 128, m0 = blockIdx.y * 128;
    const int t = threadIdx.x;
    const int w = t >> 6, L = t & 63;
    const int lm = L & 15, lq = L >> 4;
    const int wcol = t >> 1, wk0 = (t & 1) * 16;
    f32x4 acc[2][8];
#pragma unroll
    for (int mt = 0; mt < 2; mt++)
#pragma unroll
        for (int nt = 0; nt < 8; nt++) acc[mt][nt] = (f32x4){0.f, 0.f, 0.f, 0.f};

    float wreg[16];
    {
        const float* wp = &W[(size_t)wk0 * HID + n0 + wcol];
#pragma unroll
        for (int u = 0; u < 16; u++) wreg[u] = wp[(size_t)u * HID];
    }
    short8 av[2];
#pragma unroll
    for (int mt = 0; mt < 2; mt++)
        av[mt] = *(const short8*)&A[(size_t)(m0 + w * 32 + mt * 16 + lm) * HID + lq * 8];

    for (int k0 = 0; k0 < HID; k0 += 32) {
        __syncthreads();
        {
            alignas(16) unsigned short hh[16];
#pragma unroll
            for (int u = 0; u < 16; u++) hh[u] = f2b(wreg[u]);
            *(uint4*)&Wl[wcol][wk0 + 0] = *(const uint4*)&hh[0];
            *(uint4*)&Wl[wcol][wk0 + 8] = *(const uint4*)&hh[8];
        }
        const int k1 = k0 + 32;
        if (k1 < HID) {
            const float* wp = &W[(size_t)(k1 + wk0) * HID + n0 + wcol];
#pragma unroll
            for (int u = 0; u < 16; u++) wreg[u] = wp[(size_t)u * HID];
        }
        __syncthreads();
        short8 avn[2];
        if (k1 < HID) {
#pragma unroll
            for (int mt = 0; mt < 2; mt++)
                avn[mt] = *(const short8*)&A[(size_t)(m0 + w * 32 + mt * 16 + lm) * HID + k1 + lq * 8];
        }
#pragma unroll
        for (int nt = 0; nt < 8; nt++) {
            const short8 bv = *(const short8*)&Wl[nt * 16 + lm][lq * 8];
#pragma unroll
            for (int mt = 0; mt < 2; mt++)
                acc[mt][nt] = __builtin_amdgcn_mfma_f32_16x16x32_bf16(av[mt], bv, acc[mt][nt], 0, 0, 0);
        }
        if (k1 < HID) { av[0] = avn[0]; av[1] = avn[1]; }
    }
#pragma unroll
    for (int mt = 0; mt < 2; mt++)
#pragma unroll
        for (int nt = 0; nt < 8; nt++)
#pragma unroll
            for (int r = 0; r < 4; r++) {
                const int row = m0 + w * 32 + mt * 16 + lq * 4 + r;
                C[(size_t)(cRow0 + row) * HID + n0 + nt * 16 + lm] = acc[mt][nt][r];
            }
}

// ---------------------------------------------------------------------------
// Output GEMM v2 (R15-proven): 128x128 tile, W from WtoH [n][k] bf16; BK=64;
// W register double-buffered (copy-only staging).
// ---------------------------------------------------------------------------
__global__ __launch_bounds__(256) void gemm_out2(const bf16* __restrict__ A,
                                                 const bf16* __restrict__ WtoH,
                                                 float* __restrict__ C) {
    __shared__ __align__(16) unsigned short Wl[128][72];
    const int n0 = blockIdx.x * 128, m0 = blockIdx.y * 128;
    const int t = threadIdx.x;
    const int w = t >> 6, L = t & 63;
    const int lm = L & 15, lq = L >> 4;
    const int ct = t >> 1, sg = (t & 1) * 32;
    const unsigned short* __restrict__ WT = (const unsigned short*)WtoH;
    f32x4 acc[2][8];
#pragma unroll
    for (int mt = 0; mt < 2; mt++)
#pragma unroll
        for (int nt = 0; nt < 8; nt++) acc[mt][nt] = (f32x4){0.f, 0.f, 0.f, 0.f};

    uint4 wbuf[4];
    {
        const unsigned short* wp = &WT[(size_t)(n0 + ct) * HID + sg];
#pragma unroll
        for (int i = 0; i < 4; i++) wbuf[i] = *(const uint4*)&wp[i * 8];
    }
    short8 av[2][2];
#pragma unroll
    for (int mt = 0; mt < 2; mt++)
#pragma unroll
        for (int ks = 0; ks < 2; ks++)
            av[mt][ks] = *(const short8*)&A[(size_t)(m0 + w * 32 + mt * 16 + lm) * HID + ks * 32 + lq * 8];

    for (int k0 = 0; k0 < HID; k0 += 64) {
        __syncthreads();
#pragma unroll
        for (int i = 0; i < 4; i++) *(uint4*)&Wl[ct][sg + i * 8] = wbuf[i];
        const int k1 = k0 + 64;
        if (k1 < HID) {
            const unsigned short* wp = &WT[(size_t)(n0 + ct) * HID + k1 + sg];
#pragma unroll
            for (int i = 0; i < 4; i++) wbuf[i] = *(const uint4*)&wp[i * 8];
        }
        __syncthreads();
        short8 avn[2][2];
        if (k1 < HID) {
#pragma unroll
            for (int mt = 0; mt < 2; mt++)
#pragma unroll
                for (int ks = 0; ks < 2; ks++)
                    avn[mt][ks] = *(const short8*)&A[(size_t)(m0 + w * 32 + mt * 16 + lm) * HID + k1 + ks * 32 + lq * 8];
        }
#pragma unroll
        for (int ks = 0; ks < 2; ks++)
#pragma unroll
            for (int nt = 0; nt < 8; nt++) {
                const short8 bv = *(const short8*)&Wl[nt * 16 + lm][ks * 32 + lq * 8];
#pragma unroll
                for (int mt = 0; mt < 2; mt++)
                    acc[mt][nt] = __builtin_amdgcn_mfma_f32_16x16x32_bf16(av[mt][ks], bv, acc[mt][nt], 0, 0, 0);
            }
        if (k1 < HID) {
#pragma unroll
            for (int mt = 0; mt < 2; mt++)
#pragma unroll
                for (int ks = 0; ks < 2; ks++) av[mt][ks] = avn[mt][ks];
        }
    }
#pragma unroll
    for (int mt = 0; mt < 2; mt++)
#pragma unroll
        for (int nt = 0; nt < 8; nt++)
#pragma unroll
            for (int r = 0; r < 4; r++) {
                const int row = m0 + w * 32 + mt * 16 + lq * 4 + r;
                C[(size_t)row * HID + n0 + nt * 16 + lm] = acc[mt][nt][r];
            }
}

// ---------------------------------------------------------------------------
extern "C" void kernel_launch(void* const* d_in, const int* in_sizes, int n_in,
                              void* d_out, int out_size, void* d_ws, size_t ws_size,
                              hipStream_t stream) {
    const void *p_hid, *p_pos, *p_wq, *p_wk, *p_wv, *p_wo, *p_h;
    if (in_sizes[0] == 4096 && in_sizes[1] == 1048576) {
        p_h = d_in[0]; p_wk = d_in[1]; p_wo = d_in[2]; p_wq = d_in[3];
        p_wv = d_in[4]; p_hid = d_in[5]; p_pos = d_in[6];
    } else {
        p_hid = d_in[0]; p_pos = d_in[1]; p_wq = d_in[2]; p_wk = d_in[3];
        p_wv = d_in[4]; p_wo = d_in[5]; p_h = d_in[6];
    }
    const float* hidden = (const float*)p_hid;
    const int* pos_ids  = (const int*)p_pos;
    const float* Wq = (const float*)p_wq;
    const float* Wk = (const float*)p_wk;
    const float* Wv = (const float*)p_wv;
    const float* Wo = (const float*)p_wo;
    const float* Hsk = (const float*)p_h;
    float* out = (float*)d_out;

    // ws layout (bytes):
    //  FULL : Sq 131072 | Sk 32768 | topk 32768 | kf 4M | vfT 4M | qf 16.78M = 25,362,432
    //  FULL2 adds: WtqH 8M | WtqL 8M | WtkH 2M | WtkL 2M | WtvH 2M (tiled)   = 48,431,104
    //  FULL3 adds: WtoH 8M (linear [n][k])                                   = 56,819,712
    //  FULL4 adds: AhiT 16M | AloT 16M (tiled)                               = 90,374,144
    char* base = (char*)d_ws;
    float* Sq    = (float*)base;
    float* Sk    = (float*)(base + 131072);
    int*   topkb = (int*)(base + 163840);
    bf16*  kf    = (bf16*)(base + 196608);
    bf16*  vfT   = (bf16*)(base + 196608 + 4194304);
    bf16*  qbuf  = (bf16*)(base + 196608 + 8388608);
    bf16*  WtqH  = (bf16*)(base + 25362432);
    bf16*  WtqL  = (bf16*)(base + 33751040);
    bf16*  WtkH  = (bf16*)(base + 42139648);
    bf16*  WtkL  = (bf16*)(base + 44236800);
    bf16*  WtvH  = (bf16*)(base + 46333952);
    bf16*  WtoH  = (bf16*)(base + 48431104);
    bf16*  AhiT  = (bf16*)(base + 56819712);
    bf16*  AloT  = (bf16*)(base + 73596928);
    const size_t FULL_NEED  = 25362432;
    const size_t FULL2_NEED = 48431104;
    const size_t FULL3_NEED = 56819712;
    const size_t FULL4_NEED = 90374144;

    if (ws_size >= FULL2_NEED) {
        const bool hasWo = (ws_size >= FULL3_NEED);
        const bool hasA  = (ws_size >= FULL4_NEED);
        const int nA  = hasA ? 2048 : 0;
        const int nWo = hasWo ? 1024 : 0;
        prepass<<<dim3(nA + 1536 + nWo), 256, 0, stream>>>(
            Wq, Wk, Wv, Wo, hidden,
            WtqH, WtqL, WtkH, WtkL, WtvH, WtoH, AhiT, AloT, nA);
        proj4<<<dim3(24, 32), 256, 0, stream>>>(
            hidden, hasA ? AhiT : nullptr, hasA ? AloT : nullptr,
            WtqH, WtqL, WtkH, WtkL, WtvH, pos_ids, Hsk,
            qbuf, kf, vfT, Sq, Sk);
        attn_kernel<<<dim3(NBLK, NH), 256, 0, stream>>>(
            qbuf, kf, vfT, nullptr, Sq, Sk, 0, 0);
        if (hasWo)
            gemm_out2<<<dim3(HID / 128, S_LEN / 128), 256, 0, stream>>>(
                qbuf, WtoH, out);
        else
            gemm_out<<<dim3(HID / 128, S_LEN / 128), 256, 0, stream>>>(
                qbuf, Wo, out, 0);
    } else if (ws_size >= FULL_NEED) {
        proj_rope_sketch<<<dim3(24, S_LEN / 128), 256, 0, stream>>>(
            hidden, Wq, Wk, Wv, pos_ids, Hsk, qbuf, kf, vfT, Sq, Sk, 0, 0, 0);
        attn_kernel<<<dim3(NBLK, NH), 256, 0, stream>>>(
            qbuf, kf, vfT, nullptr, Sq, Sk, 0, 0);
        gemm_out<<<dim3(HID / 128, S_LEN / 128), 256, 0, stream>>>(
            qbuf, Wo, out, 0);
    } else {
        proj_rope_sketch<<<dim3(8, S_LEN / 128), 256, 0, stream>>>(
            hidden, Wq, Wk, Wv, pos_ids, Hsk, qbuf, kf, vfT, Sq, Sk, 16, 0, 0);
        for (int c = 0; c < 16; c++) {
            const int r0 = c * 256;
            proj_rope_sketch<<<dim3(16, 2), 256, 0, stream>>>(
                hidden, Wq, Wk, Wv, pos_ids, Hsk, qbuf, kf, vfT, Sq, Sk, 0, r0, r0);
            topk_kernel<<<dim3(4, NH), 64, 0, stream>>>(Sq, Sk, topkb, r0 >> 6);
            attn_kernel<<<dim3(4, NH), 256, 0, stream>>>(
                qbuf, kf, vfT, topkb, nullptr, nullptr, r0, r0);
            gemm_out<<<dim3(HID / 128, 2), 256, 0, stream>>>(
                qbuf, Wo, out, r0);
        }
    }
}